// Round 5
// baseline (150.826 us; speedup 1.0000x reference)
//
#include <hip/hip_runtime.h>

#define SRC_LEN 256
#define TRG_LEN 256
#define BATCH   32
#define HID     512
#define ATT     128
#define CSCALE  2.885390081777927f   // 2*log2(e): exp2(CSCALE*x) == exp(2x)

typedef float  f32x4  __attribute__((ext_vector_type(4)));
typedef short  bf16x8 __attribute__((ext_vector_type(8)));

// manual RNE fp32->bf16 pack (inputs finite; same rounding as cvt_pk_bf16)
__device__ inline unsigned short bfr(float x) {
    unsigned u = __builtin_bit_cast(unsigned, x);
    return (unsigned short)((u + 0x7fffu + ((u >> 16) & 1u)) >> 16);
}
__device__ inline unsigned pk2(float a, float b) {
    return (unsigned)bfr(a) | ((unsigned)bfr(b) << 16);
}

// ---------------------------------------------------------------------------
// Projection, restructured for occupancy (R3 was 1 block/CU, all latency
// exposed). 1024 blocks (4/CU): blk<512 -> enc (fixed b, 16 s-rows),
// blk>=512 -> dec (fixed b, 16 t-rows). The 16 data rows are the ONLY
// intra-block-shared operand -> staged once in LDS (full K=512 bf16,
// XOR-swizzled 16B groups, 16 KB, single __syncthreads). W fragments have no
// intra-block reuse -> loaded global->VGPR per k-step (L2-hot) + pk2 pack.
// Wave w covers W rows w*32..w*32+31 as 2 MFMA tiles of 16x16x32, K-loop 16.
// enc: mfma(A=W, B=data) => C col = s -> direct coalesced [b][a][s] store of
// E' = exp(-2*enc_att). dec: mfma(A=data, B=W) => C col = a -> direct
// [t][b][a] store of D = exp(+2*(dec_att+b_t)).
// ---------------------------------------------------------------------------
__global__ __launch_bounds__(256) void proj_mfma(
    const float* __restrict__ dec_out, const float* __restrict__ enc_outs,
    const float* __restrict__ W_s, const float* __restrict__ W_t,
    const float* __restrict__ b_t,
    float* __restrict__ encE, float* __restrict__ decD)
{
    __shared__ __align__(16) char dL[16 * 1024];   // 16 rows x 512 k bf16, swizzled

    const int tid   = threadIdx.x;
    const int blk   = blockIdx.x;
    const bool isDec = blk >= 512;
    const int idx   = blk & 511;
    const int bb    = idx & 31;
    const int r0    = (idx >> 5) * 16;             // s0 or t0
    const float* __restrict__ in = isDec ? dec_out : enc_outs;
    const float* __restrict__ W  = isDec ? W_t : W_s;

    // ---- stage 16 data rows: fp32 -> bf16, swizzled; 8 float4 per thread ----
    {
        const int row = tid >> 4;                  // 0..15
        const int fb  = tid & 15;
        const float* rp = in + ((size_t)(r0 + row) * BATCH + bb) * HID;
        #pragma unroll
        for (int i = 0; i < 8; ++i) {
            const int f4 = fb + i * 16;            // float4 index 0..127
            float4 v = *(const float4*)(rp + f4 * 4);
            uint2 u;
            u.x = pk2(v.x, v.y);
            u.y = pk2(v.z, v.w);
            const int g = f4 >> 1, half = f4 & 1;  // 16B group, 8B half
            *(uint2*)(dL + row * 1024 + ((g ^ (row & 7)) << 4) + half * 8) = u;
        }
    }
    __syncthreads();

    const int lane = tid & 63;
    const int w    = tid >> 6;        // wave id: W rows w*32 .. w*32+31
    const int l15  = lane & 15;
    const int q    = lane >> 4;       // 0..3

    f32x4 acc0 = (f32x4)0.0f, acc1 = (f32x4)0.0f;

    const float* wp = W + (size_t)(w * 32 + l15) * HID;   // tile0 row; tile1 = +16*HID

    #pragma unroll
    for (int j = 0; j < 16; ++j) {
        const int kof = j * 32 + q * 8;            // this lane's 8-k segment
        const int g   = kof >> 3;                  // = j*4 + q
        bf16x8 df = *(const bf16x8*)(dL + l15 * 1024 + ((g ^ (l15 & 7)) << 4));

        bf16x8 wf0, wf1;
        {
            const float* p0 = wp + kof;
            float4 aA = *(const float4*)(p0);
            float4 aB = *(const float4*)(p0 + 4);
            int4 u = { (int)pk2(aA.x, aA.y), (int)pk2(aA.z, aA.w),
                       (int)pk2(aB.x, aB.y), (int)pk2(aB.z, aB.w) };
            wf0 = __builtin_bit_cast(bf16x8, u);
            const float* p1 = wp + 16 * HID + kof;
            float4 bA = *(const float4*)(p1);
            float4 bB = *(const float4*)(p1 + 4);
            int4 u1 = { (int)pk2(bA.x, bA.y), (int)pk2(bA.z, bA.w),
                        (int)pk2(bB.x, bB.y), (int)pk2(bB.z, bB.w) };
            wf1 = __builtin_bit_cast(bf16x8, u1);
        }

        if (!isDec) {
            acc0 = __builtin_amdgcn_mfma_f32_16x16x32_bf16(wf0, df, acc0, 0, 0, 0);
            acc1 = __builtin_amdgcn_mfma_f32_16x16x32_bf16(wf1, df, acc1, 0, 0, 0);
        } else {
            acc0 = __builtin_amdgcn_mfma_f32_16x16x32_bf16(df, wf0, acc0, 0, 0, 0);
            acc1 = __builtin_amdgcn_mfma_f32_16x16x32_bf16(df, wf1, acc1, 0, 0, 0);
        }
    }

    if (!isDec) {
        // C: row = a-within-tile (q*4+r), col = s (l15). 16-lane-coalesced s.
        #pragma unroll
        for (int r = 0; r < 4; ++r) {
            const int a0 = w * 32 + q * 4 + r;
            encE[((size_t)bb * ATT + a0) * SRC_LEN + r0 + l15] =
                __builtin_amdgcn_exp2f(-CSCALE * acc0[r]);
            const int a1 = a0 + 16;
            encE[((size_t)bb * ATT + a1) * SRC_LEN + r0 + l15] =
                __builtin_amdgcn_exp2f(-CSCALE * acc1[r]);
        }
    } else {
        // C: row = t-within-tile (q*4+r), col = a (l15). 16-lane-coalesced a.
        const float bt0 = b_t[w * 32 + l15];
        const float bt1 = b_t[w * 32 + 16 + l15];
        #pragma unroll
        for (int r = 0; r < 4; ++r) {
            const int t = r0 + q * 4 + r;
            decD[((size_t)t * BATCH + bb) * ATT + w * 32 + l15] =
                __builtin_amdgcn_exp2f(CSCALE * (acc0[r] + bt0));
            decD[((size_t)t * BATCH + bb) * ATT + w * 32 + 16 + l15] =
                __builtin_amdgcn_exp2f(CSCALE * (acc1[r] + bt1));
        }
    }
}

// ---------------------------------------------------------------------------
// Score: out[t][b][s] = sumV - 2 * sum_a v[a]*E'/(E'+D),
// E' = exp(-2e) per-lane (lane = s, coalesced global), D,v wave-UNIFORM ->
// plain uniform-address global loads (compile to s_load, scalar K$ path).
// R3's LDS broadcast staging was the binding pipe (~25 us of ds_read_b128);
// this version uses zero LDS. Grid (64,32) = 100% wave-slot occupancy.
// ---------------------------------------------------------------------------
__global__ __launch_bounds__(256) void score_kernel(
    const float* __restrict__ encE, const float* __restrict__ decD,
    const float* __restrict__ v_a, float* __restrict__ out)
{
    const int tid = threadIdx.x;
    const int t0  = blockIdx.x * 4;
    const int b   = blockIdx.y;

    const float* __restrict__ ep  = encE + (size_t)b * ATT * SRC_LEN + tid;
    const float* __restrict__ dp0 = decD + ((size_t)(t0 + 0) * BATCH + b) * ATT;
    const float* __restrict__ dp1 = dp0 + (size_t)BATCH * ATT;
    const float* __restrict__ dp2 = dp1 + (size_t)BATCH * ATT;
    const float* __restrict__ dp3 = dp2 + (size_t)BATCH * ATT;

    // sumV once (uniform scalar loads + a few VALU adds)
    float sv = 0.f;
    #pragma unroll
    for (int g = 0; g < 32; ++g) {
        const float4 v4 = *(const float4*)(v_a + g * 4);
        sv += (v4.x + v4.y) + (v4.z + v4.w);
    }

    float acc0 = 0.f, acc1 = 0.f, acc2 = 0.f, acc3 = 0.f;

    #pragma unroll 4
    for (int g = 0; g < 32; ++g) {
        const float Ex = ep[(g * 4 + 0) * SRC_LEN];
        const float Ey = ep[(g * 4 + 1) * SRC_LEN];
        const float Ez = ep[(g * 4 + 2) * SRC_LEN];
        const float Ew = ep[(g * 4 + 3) * SRC_LEN];
        const float4 v4 = *(const float4*)(v_a + g * 4);
        const float4 d0 = *(const float4*)(dp0 + g * 4);
        const float4 d1 = *(const float4*)(dp1 + g * 4);
        const float4 d2 = *(const float4*)(dp2 + g * 4);
        const float4 d3 = *(const float4*)(dp3 + g * 4);
        const float vEx = v4.x * Ex, vEy = v4.y * Ey;
        const float vEz = v4.z * Ez, vEw = v4.w * Ew;

        acc0 = fmaf(vEx, __builtin_amdgcn_rcpf(Ex + d0.x), acc0);
        acc0 = fmaf(vEy, __builtin_amdgcn_rcpf(Ey + d0.y), acc0);
        acc0 = fmaf(vEz, __builtin_amdgcn_rcpf(Ez + d0.z), acc0);
        acc0 = fmaf(vEw, __builtin_amdgcn_rcpf(Ew + d0.w), acc0);
        acc1 = fmaf(vEx, __builtin_amdgcn_rcpf(Ex + d1.x), acc1);
        acc1 = fmaf(vEy, __builtin_amdgcn_rcpf(Ey + d1.y), acc1);
        acc1 = fmaf(vEz, __builtin_amdgcn_rcpf(Ez + d1.z), acc1);
        acc1 = fmaf(vEw, __builtin_amdgcn_rcpf(Ew + d1.w), acc1);
        acc2 = fmaf(vEx, __builtin_amdgcn_rcpf(Ex + d2.x), acc2);
        acc2 = fmaf(vEy, __builtin_amdgcn_rcpf(Ey + d2.y), acc2);
        acc2 = fmaf(vEz, __builtin_amdgcn_rcpf(Ez + d2.z), acc2);
        acc2 = fmaf(vEw, __builtin_amdgcn_rcpf(Ew + d2.w), acc2);
        acc3 = fmaf(vEx, __builtin_amdgcn_rcpf(Ex + d3.x), acc3);
        acc3 = fmaf(vEy, __builtin_amdgcn_rcpf(Ey + d3.y), acc3);
        acc3 = fmaf(vEz, __builtin_amdgcn_rcpf(Ez + d3.z), acc3);
        acc3 = fmaf(vEw, __builtin_amdgcn_rcpf(Ew + d3.w), acc3);
    }

    out[((size_t)(t0 + 0) * BATCH + b) * SRC_LEN + tid] = sv - 2.0f * acc0;
    out[((size_t)(t0 + 1) * BATCH + b) * SRC_LEN + tid] = sv - 2.0f * acc1;
    out[((size_t)(t0 + 2) * BATCH + b) * SRC_LEN + tid] = sv - 2.0f * acc2;
    out[((size_t)(t0 + 3) * BATCH + b) * SRC_LEN + tid] = sv - 2.0f * acc3;
}

extern "C" void kernel_launch(void* const* d_in, const int* in_sizes, int n_in,
                              void* d_out, int out_size, void* d_ws, size_t ws_size,
                              hipStream_t stream) {
    const float* dec_out  = (const float*)d_in[0];
    const float* enc_outs = (const float*)d_in[1];
    const float* W_s      = (const float*)d_in[2];
    const float* W_t      = (const float*)d_in[3];
    const float* b_t      = (const float*)d_in[4];
    const float* v_a      = (const float*)d_in[5];
    float* out = (float*)d_out;

    float* encE = (float*)d_ws;                              // B*A*S = 4 MB : exp(-2*enc_att)
    float* decD = encE + (size_t)BATCH * ATT * SRC_LEN;      // T*B*A = 4 MB : exp(+2*dec_att)

    proj_mfma<<<1024, 256, 0, stream>>>(dec_out, enc_outs, W_s, W_t, b_t, encE, decD);

    dim3 g3(TRG_LEN / 4, BATCH);
    score_kernel<<<g3, 256, 0, stream>>>(encE, decD, v_a, out);
}

// Round 6
// 136.345 us; speedup vs baseline: 1.1062x; 1.1062x over previous
//
#include <hip/hip_runtime.h>

#define SRC_LEN 256
#define TRG_LEN 256
#define BATCH   32
#define HID     512
#define ATT     128
#define CSCALE  2.885390081777927f   // 2*log2(e): exp2(CSCALE*x) == exp(2x)

typedef float  f32x4  __attribute__((ext_vector_type(4)));
typedef short  bf16x8 __attribute__((ext_vector_type(8)));

// manual RNE fp32->bf16 (inputs are finite normals; NaN path not needed)
__device__ inline unsigned short bfr(float x) {
    unsigned u = __builtin_bit_cast(unsigned, x);
    return (unsigned short)((u + 0x7fffu + ((u >> 16) & 1u)) >> 16);
}
__device__ inline unsigned pk2(float a, float b) {
    return (unsigned)bfr(a) | ((unsigned)bfr(b) << 16);
}

// ---------------------------------------------------------------------------
// MFMA projection — EXACT revert to the R2 version that ran inside the
// 128.2 us R3 total (coalesced LDS staging of both operands, dbuf).
// R5's per-k-step W loads were divergent (16 cache lines per dwordx4) and
// are the prime suspect for the +23 us regression; this round isolates it.
// ---------------------------------------------------------------------------
__global__ __launch_bounds__(256) void proj_mfma(
    const float* __restrict__ dec_out, const float* __restrict__ enc_outs,
    const float* __restrict__ W_s, const float* __restrict__ W_t,
    const float* __restrict__ b_t,
    float* __restrict__ encE, float* __restrict__ decD)
{
    __shared__ __align__(16) char smem[49152];
    char* aLb = smem;            // [2][64 rows][64 k] bf16 = 2 x 8192 B
    char* bLb = smem + 16384;    // [2][128 rows][64 k] bf16 = 2 x 16384 B

    const int tid   = threadIdx.x;
    const int blk   = blockIdx.x;
    const bool isDec = blk >= 128;
    const int bb    = blk & 31;
    const int r0    = ((isDec ? blk - 128 : blk) >> 5) * 64;  // s0 or t0
    const float* __restrict__ in = isDec ? dec_out : enc_outs;
    const float* __restrict__ W  = isDec ? W_t : W_s;

    const int lane   = tid & 63;
    const int w      = tid >> 6;
    const int woff_m = (w >> 1) * 32;
    const int woff_n = (w & 1) * 64;
    const int q      = lane >> 4;
    const int l15    = lane & 15;
    const int l7     = lane & 7;

    const int am  = tid >> 2, akq = tid & 3;   // A: row am (0..63), 16-k seg
    const int wn  = tid >> 1, wkh = tid & 1;   // W: row wn (0..127), 32-k half
    const float* aGp = in + ((size_t)(r0 + am) * BATCH + bb) * HID + akq * 16;
    const float* wGp = W + (size_t)wn * HID + wkh * 32;

    float4 aR[4];
    float4 wR[8];

    f32x4 acc[2][4];
    #pragma unroll
    for (int mi = 0; mi < 2; ++mi)
        #pragma unroll
        for (int ni = 0; ni < 4; ++ni) acc[mi][ni] = (f32x4)0.0f;

    #define LOADG(c)                                                     \
        {                                                                \
            _Pragma("unroll")                                            \
            for (int i = 0; i < 4; ++i)                                  \
                aR[i] = *(const float4*)(aGp + (c) * 64 + i * 4);        \
            _Pragma("unroll")                                            \
            for (int i = 0; i < 8; ++i)                                  \
                wR[i] = *(const float4*)(wGp + (c) * 64 + i * 4);        \
        }

    #define STORES(buf)                                                  \
        {                                                                \
            char* ab = aLb + (buf) * 8192;                               \
            _Pragma("unroll")                                            \
            for (int h = 0; h < 2; ++h) {                                \
                uint4 pk;                                                \
                float4 f0 = aR[2 * h], f1 = aR[2 * h + 1];               \
                pk.x = pk2(f0.x, f0.y); pk.y = pk2(f0.z, f0.w);          \
                pk.z = pk2(f1.x, f1.y); pk.w = pk2(f1.z, f1.w);          \
                int g = akq * 2 + h;                                     \
                *(uint4*)(ab + am * 128 + ((g ^ (am & 7)) * 16)) = pk;   \
            }                                                            \
            char* bp = bLb + (buf) * 16384;                              \
            _Pragma("unroll")                                            \
            for (int h = 0; h < 4; ++h) {                                \
                uint4 pk;                                                \
                float4 f0 = wR[2 * h], f1 = wR[2 * h + 1];               \
                pk.x = pk2(f0.x, f0.y); pk.y = pk2(f0.z, f0.w);          \
                pk.z = pk2(f1.x, f1.y); pk.w = pk2(f1.z, f1.w);          \
                int g = wkh * 4 + h;                                     \
                *(uint4*)(bp + wn * 128 + ((g ^ (wn & 7)) * 16)) = pk;   \
            }                                                            \
        }

    LOADG(0);
    STORES(0);
    __syncthreads();

    for (int c = 0; c < 8; ++c) {
        if (c < 7) LOADG(c + 1);
        const char* ab = aLb + (c & 1) * 8192;
        const char* bp = bLb + (c & 1) * 16384;
        #pragma unroll
        for (int s = 0; s < 2; ++s) {
            bf16x8 af[2], bfv[4];
            const int sw = ((s * 4 + q) ^ l7) * 16;
            #pragma unroll
            for (int mi = 0; mi < 2; ++mi)
                af[mi] = *(const bf16x8*)(ab + (woff_m + mi * 16 + l15) * 128 + sw);
            #pragma unroll
            for (int ni = 0; ni < 4; ++ni)
                bfv[ni] = *(const bf16x8*)(bp + (woff_n + ni * 16 + l15) * 128 + sw);
            #pragma unroll
            for (int mi = 0; mi < 2; ++mi)
                #pragma unroll
                for (int ni = 0; ni < 4; ++ni)
                    acc[mi][ni] = __builtin_amdgcn_mfma_f32_16x16x32_bf16(
                        af[mi], bfv[ni], acc[mi][ni], 0, 0, 0);
        }
        if (c < 7) STORES((c + 1) & 1);
        __syncthreads();
    }

    if (!isDec) {
        // E' = exp(-2*enc_att), transposed store via padded LDS (stride 129)
        float* T = (float*)smem;
        #pragma unroll
        for (int mi = 0; mi < 2; ++mi)
            #pragma unroll
            for (int ni = 0; ni < 4; ++ni)
                #pragma unroll
                for (int r = 0; r < 4; ++r) {
                    const int ml = woff_m + mi * 16 + q * 4 + r;
                    const int nl = woff_n + ni * 16 + l15;
                    T[ml * 129 + nl] = __builtin_amdgcn_exp2f(-CSCALE * acc[mi][ni][r]);
                }
        __syncthreads();
        const int m  = tid & 63;
        const int n0 = tid >> 6;
        #pragma unroll
        for (int p = 0; p < 32; ++p) {
            const int n = n0 + p * 4;
            encE[((size_t)(bb * ATT + n)) * SRC_LEN + r0 + m] = T[m * 129 + n];
        }
    } else {
        // D = exp(+2*(dec_att + b_t)), natural [t][b][a] store
        float bt[4];
        #pragma unroll
        for (int ni = 0; ni < 4; ++ni) bt[ni] = b_t[woff_n + ni * 16 + l15];
        #pragma unroll
        for (int mi = 0; mi < 2; ++mi)
            #pragma unroll
            for (int ni = 0; ni < 4; ++ni)
                #pragma unroll
                for (int r = 0; r < 4; ++r) {
                    const int ml = woff_m + mi * 16 + q * 4 + r;
                    const int nl = woff_n + ni * 16 + l15;
                    decD[((size_t)(r0 + ml) * BATCH + bb) * ATT + nl] =
                        __builtin_amdgcn_exp2f(CSCALE * (acc[mi][ni][r] + bt[ni]));
                }
    }
    #undef LOADG
    #undef STORES
}

// ---------------------------------------------------------------------------
// Score (unchanged from R4): out = sumV - 2*sum_a v[a]*E'/(E'+D).
// E' per-lane coalesced global; D,v wave-uniform loads; zero LDS.
// ---------------------------------------------------------------------------
__global__ __launch_bounds__(256) void score_kernel(
    const float* __restrict__ encE, const float* __restrict__ decD,
    const float* __restrict__ v_a, float* __restrict__ out)
{
    const int tid = threadIdx.x;
    const int t0  = blockIdx.x * 4;
    const int b   = blockIdx.y;

    const float* __restrict__ ep  = encE + (size_t)b * ATT * SRC_LEN + tid;
    const float* __restrict__ dp0 = decD + ((size_t)(t0 + 0) * BATCH + b) * ATT;
    const float* __restrict__ dp1 = dp0 + (size_t)BATCH * ATT;
    const float* __restrict__ dp2 = dp1 + (size_t)BATCH * ATT;
    const float* __restrict__ dp3 = dp2 + (size_t)BATCH * ATT;

    float sv = 0.f;
    #pragma unroll
    for (int g = 0; g < 32; ++g) {
        const float4 v4 = *(const float4*)(v_a + g * 4);
        sv += (v4.x + v4.y) + (v4.z + v4.w);
    }

    float acc0 = 0.f, acc1 = 0.f, acc2 = 0.f, acc3 = 0.f;

    #pragma unroll 4
    for (int g = 0; g < 32; ++g) {
        const float Ex = ep[(g * 4 + 0) * SRC_LEN];
        const float Ey = ep[(g * 4 + 1) * SRC_LEN];
        const float Ez = ep[(g * 4 + 2) * SRC_LEN];
        const float Ew = ep[(g * 4 + 3) * SRC_LEN];
        const float4 v4 = *(const float4*)(v_a + g * 4);
        const float4 d0 = *(const float4*)(dp0 + g * 4);
        const float4 d1 = *(const float4*)(dp1 + g * 4);
        const float4 d2 = *(const float4*)(dp2 + g * 4);
        const float4 d3 = *(const float4*)(dp3 + g * 4);
        const float vEx = v4.x * Ex, vEy = v4.y * Ey;
        const float vEz = v4.z * Ez, vEw = v4.w * Ew;

        acc0 = fmaf(vEx, __builtin_amdgcn_rcpf(Ex + d0.x), acc0);
        acc0 = fmaf(vEy, __builtin_amdgcn_rcpf(Ey + d0.y), acc0);
        acc0 = fmaf(vEz, __builtin_amdgcn_rcpf(Ez + d0.z), acc0);
        acc0 = fmaf(vEw, __builtin_amdgcn_rcpf(Ew + d0.w), acc0);
        acc1 = fmaf(vEx, __builtin_amdgcn_rcpf(Ex + d1.x), acc1);
        acc1 = fmaf(vEy, __builtin_amdgcn_rcpf(Ey + d1.y), acc1);
        acc1 = fmaf(vEz, __builtin_amdgcn_rcpf(Ez + d1.z), acc1);
        acc1 = fmaf(vEw, __builtin_amdgcn_rcpf(Ew + d1.w), acc1);
        acc2 = fmaf(vEx, __builtin_amdgcn_rcpf(Ex + d2.x), acc2);
        acc2 = fmaf(vEy, __builtin_amdgcn_rcpf(Ey + d2.y), acc2);
        acc2 = fmaf(vEz, __builtin_amdgcn_rcpf(Ez + d2.z), acc2);
        acc2 = fmaf(vEw, __builtin_amdgcn_rcpf(Ew + d2.w), acc2);
        acc3 = fmaf(vEx, __builtin_amdgcn_rcpf(Ex + d3.x), acc3);
        acc3 = fmaf(vEy, __builtin_amdgcn_rcpf(Ey + d3.y), acc3);
        acc3 = fmaf(vEz, __builtin_amdgcn_rcpf(Ez + d3.z), acc3);
        acc3 = fmaf(vEw, __builtin_amdgcn_rcpf(Ew + d3.w), acc3);
    }

    out[((size_t)(t0 + 0) * BATCH + b) * SRC_LEN + tid] = sv - 2.0f * acc0;
    out[((size_t)(t0 + 1) * BATCH + b) * SRC_LEN + tid] = sv - 2.0f * acc1;
    out[((size_t)(t0 + 2) * BATCH + b) * SRC_LEN + tid] = sv - 2.0f * acc2;
    out[((size_t)(t0 + 3) * BATCH + b) * SRC_LEN + tid] = sv - 2.0f * acc3;
}

extern "C" void kernel_launch(void* const* d_in, const int* in_sizes, int n_in,
                              void* d_out, int out_size, void* d_ws, size_t ws_size,
                              hipStream_t stream) {
    const float* dec_out  = (const float*)d_in[0];
    const float* enc_outs = (const float*)d_in[1];
    const float* W_s      = (const float*)d_in[2];
    const float* W_t      = (const float*)d_in[3];
    const float* b_t      = (const float*)d_in[4];
    const float* v_a      = (const float*)d_in[5];
    float* out = (float*)d_out;

    float* encE = (float*)d_ws;                              // B*A*S = 4 MB : exp(-2*enc_att)
    float* decD = encE + (size_t)BATCH * ATT * SRC_LEN;      // T*B*A = 4 MB : exp(+2*dec_att)

    proj_mfma<<<256, 256, 0, stream>>>(dec_out, enc_outs, W_s, W_t, b_t, encE, decD);

    dim3 g3(TRG_LEN / 4, BATCH);
    score_kernel<<<g3, 256, 0, stream>>>(encE, decD, v_a, out);
}